// Round 1
// baseline (561.751 us; speedup 1.0000x reference)
//
#include <hip/hip_runtime.h>
#include <stdint.h>

typedef unsigned short u16;
typedef short short8 __attribute__((ext_vector_type(8)));
typedef short short4v __attribute__((ext_vector_type(4)));
typedef float float4v __attribute__((ext_vector_type(4)));

#define HW 4096
#define SCL 0.18033688011112042f   /* 0.125 * log2(e) */

static __device__ __forceinline__ u16 f2bf(float f) {
  union { float f; uint32_t u; } v; v.f = f;
  uint32_t r = v.u + 0x7fffu + ((v.u >> 16) & 1u);
  return (u16)(r >> 16);
}

// ---- kernel 1: x [4,256,4096] f32 -> Xtp [4,66,66,256] bf16 (spatially padded; halo pre-zeroed)
__global__ __launch_bounds__(256) void k_xt(const float* __restrict__ x, u16* __restrict__ Xtp) {
  __shared__ float t[32][33];
  const int b = blockIdx.z, c0 = blockIdx.y * 32, p0 = blockIdx.x * 32;
  const int tid = threadIdx.x;
  const int l8 = tid >> 5, lp = tid & 31;
#pragma unroll
  for (int i = 0; i < 4; i++) {
    int c = l8 + i * 8;
    t[c][lp] = x[(size_t)(b * 256 + c0 + c) * HW + p0 + lp];
  }
  __syncthreads();
#pragma unroll
  for (int i = 0; i < 4; i++) {
    int p = l8 + i * 8;
    int pp = p0 + p;
    int y = pp >> 6, xx = pp & 63;
    Xtp[((size_t)(b * 66 + y + 1) * 66 + (xx + 1)) * 256 + c0 + lp] = f2bf(t[lp][p]);
  }
}

// ---- kernel 2: repack weights -> Wt [9][384][256] bf16 (ci contiguous), bcat[384] f32
__global__ __launch_bounds__(256) void k_wprep(const float* __restrict__ qw, const float* __restrict__ qb,
    const float* __restrict__ kw, const float* __restrict__ kb,
    const float* __restrict__ vw, const float* __restrict__ vb,
    u16* __restrict__ Wt, float* __restrict__ bcat) {
  int tid = blockIdx.x * 256 + threadIdx.x;
  if (tid < 9 * 384 * 256) {
    int ci = tid & 255;
    int n = (tid >> 8) % 384;
    int off = tid / (384 * 256);
    float val;
    if (n < 64)       val = qw[(size_t)n * 2304 + ci * 9 + off];
    else if (n < 128) val = kw[(size_t)(n - 64) * 2304 + ci * 9 + off];
    else              val = vw[(size_t)(n - 128) * 2304 + ci * 9 + off];
    Wt[tid] = f2bf(val);
  }
  if (tid < 384) bcat[tid] = (tid < 64) ? qb[tid] : (tid < 128) ? kb[tid - 64] : vb[tid - 128];
}

// ---- kernel 3: fused QKV conv as 9 shifted GEMMs. Per block: 128 pos x 128 outch, K = 9*256.
// ntile 0 -> q|k, written channel-last Qt/Kt[b][pos][64] via swapped-operand MFMA (C^T layout).
// ntile 1,2 -> v, written channel-first Vcf[b][c][pos] via normal MFMA.
__global__ __launch_bounds__(256) void k_conv(const u16* __restrict__ Xtp,
    const u16* __restrict__ Wt, const float* __restrict__ bcat,
    u16* __restrict__ Qt, u16* __restrict__ Kt, u16* __restrict__ Vcf) {
  __shared__ u16 Als[128][40];   // 32 k + 8 pad  (20-dword stride -> 2-way only)
  __shared__ u16 Bls[128][40];
  const int tid = threadIdx.x;
  const int b = blockIdx.z, ntile = blockIdx.y;
  const int p0 = blockIdx.x * 128, n0 = ntile * 128;
  const int sr = tid >> 1, sh = tid & 1;
  const int pos = p0 + sr, py = pos >> 6, px = pos & 63;
  const u16* abase = Xtp + ((size_t)(b * 66 + py) * 66 + px) * 256 + sh * 16;
  const u16* bbase = Wt + (size_t)(n0 + sr) * 256 + sh * 16;
  const int w = tid >> 6, lane = tid & 63, l16 = lane & 15, quad = lane >> 4;
  const int mw = (w & 1) * 64, nw = (w >> 1) * 64;
  float4v acc[4][4];
  const float4v zz = {0.f, 0.f, 0.f, 0.f};
#pragma unroll
  for (int i = 0; i < 4; i++)
#pragma unroll
    for (int j = 0; j < 4; j++) acc[i][j] = zz;

  for (int ks = 0; ks < 72; ks++) {
    const int off = ks >> 3, cb = ks & 7;
    const int dy = off / 3, dx = off - dy * 3;
    const u16* asrc = abase + (size_t)(dy * 66 + dx) * 256 + cb * 32;
    const u16* bsrc = bbase + (size_t)off * (384 * 256) + cb * 32;
    short8 a0 = ((const short8*)asrc)[0];
    short8 a1 = ((const short8*)asrc)[1];
    short8 w0 = ((const short8*)bsrc)[0];
    short8 w1 = ((const short8*)bsrc)[1];
    *(short8*)&Als[sr][sh * 16] = a0;
    *(short8*)&Als[sr][sh * 16 + 8] = a1;
    *(short8*)&Bls[sr][sh * 16] = w0;
    *(short8*)&Bls[sr][sh * 16 + 8] = w1;
    __syncthreads();
    short8 af[4], bfv[4];
#pragma unroll
    for (int mt = 0; mt < 4; mt++) af[mt] = *(const short8*)&Als[mw + mt * 16 + l16][quad * 8];
#pragma unroll
    for (int nt = 0; nt < 4; nt++) bfv[nt] = *(const short8*)&Bls[nw + nt * 16 + l16][quad * 8];
    if (ntile == 0) {
#pragma unroll
      for (int mt = 0; mt < 4; mt++)
#pragma unroll
        for (int nt = 0; nt < 4; nt++)
          acc[mt][nt] = __builtin_amdgcn_mfma_f32_16x16x32_bf16(bfv[nt], af[mt], acc[mt][nt], 0, 0, 0);
    } else {
#pragma unroll
      for (int mt = 0; mt < 4; mt++)
#pragma unroll
        for (int nt = 0; nt < 4; nt++)
          acc[mt][nt] = __builtin_amdgcn_mfma_f32_16x16x32_bf16(af[mt], bfv[nt], acc[mt][nt], 0, 0, 0);
    }
    __syncthreads();
  }

  if (ntile == 0) {
    // D rows = out-channel, cols = pos  -> lane writes 4 consecutive channels (8B)
#pragma unroll
    for (int mt = 0; mt < 4; mt++) {
      const int p = p0 + mw + mt * 16 + l16;
#pragma unroll
      for (int nt = 0; nt < 4; nt++) {
        const int nb = nw + nt * 16 + quad * 4;
        short4v o;
#pragma unroll
        for (int r = 0; r < 4; r++) o[r] = (short)f2bf(acc[mt][nt][r] + bcat[nb + r]);
        u16* dst = (nb < 64) ? (Qt + (size_t)(b * HW + p) * 64 + nb)
                             : (Kt + (size_t)(b * HW + p) * 64 + (nb - 64));
        *(short4v*)dst = o;
      }
    }
  } else {
    // D rows = pos, cols = channel -> lane writes 4 consecutive positions (8B) channel-first
#pragma unroll
    for (int mt = 0; mt < 4; mt++) {
      const int pb = p0 + mw + mt * 16 + quad * 4;
#pragma unroll
      for (int nt = 0; nt < 4; nt++) {
        const int c = (ntile - 1) * 128 + nw + nt * 16 + l16;
        const float bias = bcat[128 + c];
        short4v o;
#pragma unroll
        for (int r = 0; r < 4; r++) o[r] = (short)f2bf(acc[mt][nt][r] + bias);
        *(short4v*)(Vcf + (size_t)(b * 256 + c) * HW + pb) = o;
      }
    }
  }
}

// ---- kernel 4: flash attention. 1 WG per (batch, 64-query tile). 4 waves; wave w owns
// 16-wide j slice for QK and 64 output channels for PV. j-tiles of 64.
__global__ __launch_bounds__(256, 1) void k_attn(const u16* __restrict__ Qt,
    const u16* __restrict__ Kt, const u16* __restrict__ Vcf, float* __restrict__ out) {
  __shared__ u16 Kls[64][72];    // 9216 B
  __shared__ u16 Vls[256][72];   // 36864 B
  __shared__ u16 Pls[64][72];    // 9216 B
  __shared__ float wmax[4][64];
  __shared__ float wsum[4][64];
  __shared__ float mrun[64], lrun[64], alf[64];
  const int tid = threadIdx.x;
  const int b = blockIdx.y, i0 = blockIdx.x * 64;
  const int w = tid >> 6, lane = tid & 63, l16 = lane & 15, quad = lane >> 4;
  if (tid < 64) { mrun[tid] = -1e30f; lrun[tid] = 0.f; }

  short8 qf[4][2];
#pragma unroll
  for (int mt = 0; mt < 4; mt++)
#pragma unroll
    for (int kk = 0; kk < 2; kk++)
      qf[mt][kk] = *(const short8*)(Qt + (size_t)(b * HW + i0 + mt * 16 + l16) * 64 + kk * 32 + quad * 8);

  float4v of[4][4];
  const float4v zz = {0.f, 0.f, 0.f, 0.f};
#pragma unroll
  for (int i = 0; i < 4; i++)
#pragma unroll
    for (int j = 0; j < 4; j++) of[i][j] = zz;

  for (int jt = 0; jt < 64; jt++) {
    const int j0 = jt * 64;
    __syncthreads();                       // B0: prev PV done; (jt==0: init visible)
#pragma unroll
    for (int it = 0; it < 2; it++) {       // stage K: 64 rows x 64 bf16
      int c2 = it * 256 + tid, r = c2 >> 3, q = c2 & 7;
      *(short8*)&Kls[r][q * 8] = *(const short8*)(Kt + (size_t)(b * HW + j0 + r) * 64 + q * 8);
    }
#pragma unroll
    for (int it = 0; it < 8; it++) {       // stage V: 256 rows x 64 bf16
      int c2 = it * 256 + tid, r = c2 >> 3, q = c2 & 7;
      *(short8*)&Vls[r][q * 8] = *(const short8*)(Vcf + (size_t)(b * 256 + r) * HW + j0 + q * 8);
    }
    __syncthreads();                       // B1: staging visible

    // QK^T for this wave's 16-wide j slice
    float4v sf[4];
#pragma unroll
    for (int mt = 0; mt < 4; mt++) sf[mt] = zz;
    short8 kb0 = *(const short8*)&Kls[w * 16 + l16][quad * 8];
    short8 kb1 = *(const short8*)&Kls[w * 16 + l16][32 + quad * 8];
#pragma unroll
    for (int mt = 0; mt < 4; mt++) {
      sf[mt] = __builtin_amdgcn_mfma_f32_16x16x32_bf16(qf[mt][0], kb0, sf[mt], 0, 0, 0);
      sf[mt] = __builtin_amdgcn_mfma_f32_16x16x32_bf16(qf[mt][1], kb1, sf[mt], 0, 0, 0);
    }
    // per-row max of this slice (reduce across 16 col-lanes)
#pragma unroll
    for (int mt = 0; mt < 4; mt++) {
#pragma unroll
      for (int r = 0; r < 4; r++) {
        float v = sf[mt][r];
        v = fmaxf(v, __shfl_xor(v, 1, 16));
        v = fmaxf(v, __shfl_xor(v, 2, 16));
        v = fmaxf(v, __shfl_xor(v, 4, 16));
        v = fmaxf(v, __shfl_xor(v, 8, 16));
        if (l16 == 0) wmax[w][mt * 16 + quad * 4 + r] = v;
      }
    }
    __syncthreads();                       // B2: wmax visible
    if (tid < 64) {
      float tm = fmaxf(fmaxf(wmax[0][tid], wmax[1][tid]), fmaxf(wmax[2][tid], wmax[3][tid])) * SCL;
      float mo = mrun[tid], mn = fmaxf(mo, tm);
      alf[tid] = exp2f(mo - mn);
      mrun[tid] = mn;
    }
    __syncthreads();                       // B3: mrun/alf visible

    // P = exp2(s*SCL - m); write bf16 to LDS; per-wave row sums; rescale O
#pragma unroll
    for (int mt = 0; mt < 4; mt++) {
      float ps[4];
#pragma unroll
      for (int r = 0; r < 4; r++) {
        int row = mt * 16 + quad * 4 + r;
        float p = exp2f(sf[mt][r] * SCL - mrun[row]);
        Pls[row][w * 16 + l16] = f2bf(p);
        ps[r] = p;
      }
#pragma unroll
      for (int r = 0; r < 4; r++) {
        float v = ps[r];
        v += __shfl_xor(v, 1, 16);
        v += __shfl_xor(v, 2, 16);
        v += __shfl_xor(v, 4, 16);
        v += __shfl_xor(v, 8, 16);
        if (l16 == 0) wsum[w][mt * 16 + quad * 4 + r] = v;
      }
#pragma unroll
      for (int r = 0; r < 4; r++) {
        float a = alf[mt * 16 + quad * 4 + r];
#pragma unroll
        for (int nt = 0; nt < 4; nt++) of[mt][nt][r] *= a;
      }
    }
    __syncthreads();                       // B4: Pls/wsum visible
    if (tid < 64)
      lrun[tid] = lrun[tid] * alf[tid] + (wsum[0][tid] + wsum[1][tid] + wsum[2][tid] + wsum[3][tid]);

    // PV: O[i][c] += P[i][j] * V[c][j]
#pragma unroll
    for (int kk = 0; kk < 2; kk++) {
      short8 pa[4];
#pragma unroll
      for (int mt = 0; mt < 4; mt++) pa[mt] = *(const short8*)&Pls[mt * 16 + l16][kk * 32 + quad * 8];
#pragma unroll
      for (int nt = 0; nt < 4; nt++) {
        short8 vbf = *(const short8*)&Vls[w * 64 + nt * 16 + l16][kk * 32 + quad * 8];
#pragma unroll
        for (int mt = 0; mt < 4; mt++)
          of[mt][nt] = __builtin_amdgcn_mfma_f32_16x16x32_bf16(pa[mt], vbf, of[mt][nt], 0, 0, 0);
      }
    }
  }
  __syncthreads();                         // lrun final visible

#pragma unroll
  for (int mt = 0; mt < 4; mt++) {
    float li[4];
#pragma unroll
    for (int r = 0; r < 4; r++) li[r] = 1.0f / lrun[mt * 16 + quad * 4 + r];
#pragma unroll
    for (int nt = 0; nt < 4; nt++) {
      const int c = w * 64 + nt * 16 + l16;
      float4v o;
#pragma unroll
      for (int r = 0; r < 4; r++) o[r] = of[mt][nt][r] * li[r];
      *(float4v*)(out + (size_t)(b * 256 + c) * HW + i0 + mt * 16 + quad * 4) = o;
    }
  }
}

extern "C" void kernel_launch(void* const* d_in, const int* in_sizes, int n_in,
                              void* d_out, int out_size, void* d_ws, size_t ws_size,
                              hipStream_t stream) {
  const float* x  = (const float*)d_in[0];
  const float* qw = (const float*)d_in[1];
  const float* qb = (const float*)d_in[2];
  const float* kw = (const float*)d_in[3];
  const float* kb = (const float*)d_in[4];
  const float* vw = (const float*)d_in[5];
  const float* vb = (const float*)d_in[6];
  float* out = (float*)d_out;
  char* ws = (char*)d_ws;
  // workspace layout (bytes):
  //   Xtp : 4*66*66*256*2 = 8,921,088
  //   Wt  : 9*384*256*2   = 1,769,472
  //   bcat: 384*4         = 1,536
  //   Qt  : 4*4096*64*2   = 2,097,152
  //   Kt  : 4*4096*64*2   = 2,097,152
  //   Vcf : 4*256*4096*2  = 8,388,608   (total ~23.3 MB)
  u16*   Xtp = (u16*)(ws);
  u16*   Wt  = (u16*)(ws + 8921088);
  float* bc  = (float*)(ws + 10690560);
  u16*   Qt  = (u16*)(ws + 10692096);
  u16*   Kt  = (u16*)(ws + 12789248);
  u16*   Vcf = (u16*)(ws + 14886400);

  hipMemsetAsync(Xtp, 0, 8921088, stream);  // zero the spatial halo
  k_xt  <<<dim3(128, 8, 4), 256, 0, stream>>>(x, Xtp);
  k_wprep<<<3456, 256, 0, stream>>>(qw, qb, kw, kb, vw, vb, Wt, bc);
  k_conv<<<dim3(32, 3, 4), 256, 0, stream>>>(Xtp, Wt, bc, Qt, Kt, Vcf);
  k_attn<<<dim3(64, 4), 256, 0, stream>>>(Qt, Kt, Vcf, out);
}

// Round 2
// 438.069 us; speedup vs baseline: 1.2823x; 1.2823x over previous
//
#include <hip/hip_runtime.h>
#include <stdint.h>

typedef unsigned short u16;
typedef short short8 __attribute__((ext_vector_type(8)));
typedef short short4v __attribute__((ext_vector_type(4)));
typedef float float4v __attribute__((ext_vector_type(4)));

#define HW 4096
#define SCL 0.18033688011112042f   /* 0.125 * log2(e) */

static __device__ __forceinline__ u16 f2bf(float f) {
  union { float f; uint32_t u; } v; v.f = f;
  uint32_t r = v.u + 0x7fffu + ((v.u >> 16) & 1u);
  return (u16)(r >> 16);
}
// fast round (ties-away) — fine for p in [0,1]
static __device__ __forceinline__ u16 f2bf_fast(float f) {
  union { float f; uint32_t u; } v; v.f = f;
  return (u16)((v.u + 0x8000u) >> 16);
}

// ---- kernel 1: x [4,256,4096] f32 -> Xtp [4,66,66,256] bf16 (spatially padded; halo pre-zeroed)
__global__ __launch_bounds__(256) void k_xt(const float* __restrict__ x, u16* __restrict__ Xtp) {
  __shared__ float t[32][33];
  const int b = blockIdx.z, c0 = blockIdx.y * 32, p0 = blockIdx.x * 32;
  const int tid = threadIdx.x;
  const int l8 = tid >> 5, lp = tid & 31;
#pragma unroll
  for (int i = 0; i < 4; i++) {
    int c = l8 + i * 8;
    t[c][lp] = x[(size_t)(b * 256 + c0 + c) * HW + p0 + lp];
  }
  __syncthreads();
#pragma unroll
  for (int i = 0; i < 4; i++) {
    int p = l8 + i * 8;
    int pp = p0 + p;
    int y = pp >> 6, xx = pp & 63;
    Xtp[((size_t)(b * 66 + y + 1) * 66 + (xx + 1)) * 256 + c0 + lp] = f2bf(t[lp][p]);
  }
}

// ---- kernel 2: repack weights -> Wt [9][384][256] bf16 (ci contiguous), bcat[384] f32
__global__ __launch_bounds__(256) void k_wprep(const float* __restrict__ qw, const float* __restrict__ qb,
    const float* __restrict__ kw, const float* __restrict__ kb,
    const float* __restrict__ vw, const float* __restrict__ vb,
    u16* __restrict__ Wt, float* __restrict__ bcat) {
  int tid = blockIdx.x * 256 + threadIdx.x;
  if (tid < 9 * 384 * 256) {
    int ci = tid & 255;
    int n = (tid >> 8) % 384;
    int off = tid / (384 * 256);
    float val;
    if (n < 64)       val = qw[(size_t)n * 2304 + ci * 9 + off];
    else if (n < 128) val = kw[(size_t)(n - 64) * 2304 + ci * 9 + off];
    else              val = vw[(size_t)(n - 128) * 2304 + ci * 9 + off];
    Wt[tid] = f2bf(val);
  }
  if (tid < 384) bcat[tid] = (tid < 64) ? qb[tid] : (tid < 128) ? kb[tid - 64] : vb[tid - 128];
}

// ---- kernel 3: fused QKV conv as 9 shifted GEMMs (unchanged this round)
__global__ __launch_bounds__(256) void k_conv(const u16* __restrict__ Xtp,
    const u16* __restrict__ Wt, const float* __restrict__ bcat,
    u16* __restrict__ Qt, u16* __restrict__ Kt, u16* __restrict__ Vcf) {
  __shared__ u16 Als[128][40];
  __shared__ u16 Bls[128][40];
  const int tid = threadIdx.x;
  const int b = blockIdx.z, ntile = blockIdx.y;
  const int p0 = blockIdx.x * 128, n0 = ntile * 128;
  const int sr = tid >> 1, sh = tid & 1;
  const int pos = p0 + sr, py = pos >> 6, px = pos & 63;
  const u16* abase = Xtp + ((size_t)(b * 66 + py) * 66 + px) * 256 + sh * 16;
  const u16* bbase = Wt + (size_t)(n0 + sr) * 256 + sh * 16;
  const int w = tid >> 6, lane = tid & 63, l16 = lane & 15, quad = lane >> 4;
  const int mw = (w & 1) * 64, nw = (w >> 1) * 64;
  float4v acc[4][4];
  const float4v zz = {0.f, 0.f, 0.f, 0.f};
#pragma unroll
  for (int i = 0; i < 4; i++)
#pragma unroll
    for (int j = 0; j < 4; j++) acc[i][j] = zz;

  for (int ks = 0; ks < 72; ks++) {
    const int off = ks >> 3, cb = ks & 7;
    const int dy = off / 3, dx = off - dy * 3;
    const u16* asrc = abase + (size_t)(dy * 66 + dx) * 256 + cb * 32;
    const u16* bsrc = bbase + (size_t)off * (384 * 256) + cb * 32;
    short8 a0 = ((const short8*)asrc)[0];
    short8 a1 = ((const short8*)asrc)[1];
    short8 w0 = ((const short8*)bsrc)[0];
    short8 w1 = ((const short8*)bsrc)[1];
    *(short8*)&Als[sr][sh * 16] = a0;
    *(short8*)&Als[sr][sh * 16 + 8] = a1;
    *(short8*)&Bls[sr][sh * 16] = w0;
    *(short8*)&Bls[sr][sh * 16 + 8] = w1;
    __syncthreads();
    short8 af[4], bfv[4];
#pragma unroll
    for (int mt = 0; mt < 4; mt++) af[mt] = *(const short8*)&Als[mw + mt * 16 + l16][quad * 8];
#pragma unroll
    for (int nt = 0; nt < 4; nt++) bfv[nt] = *(const short8*)&Bls[nw + nt * 16 + l16][quad * 8];
    if (ntile == 0) {
#pragma unroll
      for (int mt = 0; mt < 4; mt++)
#pragma unroll
        for (int nt = 0; nt < 4; nt++)
          acc[mt][nt] = __builtin_amdgcn_mfma_f32_16x16x32_bf16(bfv[nt], af[mt], acc[mt][nt], 0, 0, 0);
    } else {
#pragma unroll
      for (int mt = 0; mt < 4; mt++)
#pragma unroll
        for (int nt = 0; nt < 4; nt++)
          acc[mt][nt] = __builtin_amdgcn_mfma_f32_16x16x32_bf16(af[mt], bfv[nt], acc[mt][nt], 0, 0, 0);
    }
    __syncthreads();
  }

  if (ntile == 0) {
#pragma unroll
    for (int mt = 0; mt < 4; mt++) {
      const int p = p0 + mw + mt * 16 + l16;
#pragma unroll
      for (int nt = 0; nt < 4; nt++) {
        const int nb = nw + nt * 16 + quad * 4;
        short4v o;
#pragma unroll
        for (int r = 0; r < 4; r++) o[r] = (short)f2bf(acc[mt][nt][r] + bcat[nb + r]);
        u16* dst = (nb < 64) ? (Qt + (size_t)(b * HW + p) * 64 + nb)
                             : (Kt + (size_t)(b * HW + p) * 64 + (nb - 64));
        *(short4v*)dst = o;
      }
    }
  } else {
#pragma unroll
    for (int mt = 0; mt < 4; mt++) {
      const int pb = p0 + mw + mt * 16 + quad * 4;
#pragma unroll
      for (int nt = 0; nt < 4; nt++) {
        const int c = (ntile - 1) * 128 + nw + nt * 16 + l16;
        const float bias = bcat[128 + c];
        short4v o;
#pragma unroll
        for (int r = 0; r < 4; r++) o[r] = (short)f2bf(acc[mt][nt][r] + bias);
        *(short4v*)(Vcf + (size_t)(b * 256 + c) * HW + pb) = o;
      }
    }
  }
}

// ---- kernel 4: barrier-free flash attention.
// Grid (64, 4) x 256 threads. Wave w of block (bx,b) owns query rows
// i0 = bx*64 + w*16 .. +16 and runs the whole j-loop privately: no
// __syncthreads anywhere. K/V fragments gathered from global (L1-shared
// across the 4 waves); P round-trips a per-wave LDS buffer
// (wave-synchronous DS, order pinned via sched_barrier + lgkmcnt(0)).
// PV uses mfma(V,P) so D = O^T[c][i]: 1/l is lane-uniform, stores are
// 64B-per-quad coalesced.
__global__ __launch_bounds__(256, 1) void k_attn(const u16* __restrict__ Qt,
    const u16* __restrict__ Kt, const u16* __restrict__ Vcf, float* __restrict__ out) {
  __shared__ u16 Pls[4][16][68];   // per-wave P tile [i][j], 8704 B total
  const int tid = threadIdx.x;
  const int b = blockIdx.y, ib = blockIdx.x * 64;
  const int w = tid >> 6, lane = tid & 63, l16 = lane & 15, quad = lane >> 4;
  const int i0 = ib + w * 16;

  const u16* Kb = Kt + (size_t)b * HW * 64;
  const u16* Vb = Vcf + (size_t)b * 256 * HW;

  // Q fragment: A[m=l16][k=quad*8+t]
  short8 qf[2];
  {
    const u16* qp = Qt + (size_t)(b * HW + i0 + l16) * 64 + quad * 8;
    qf[0] = *(const short8*)qp;
    qf[1] = *(const short8*)(qp + 32);
  }

  float4v of[16];
  const float4v zz = {0.f, 0.f, 0.f, 0.f};
#pragma unroll
  for (int nt = 0; nt < 16; nt++) of[nt] = zz;
  float lsum[4] = {0.f, 0.f, 0.f, 0.f};
  float m = -1e30f;

  // preload K tile 0: B[k=d=quad*8+t][n=j=l16] per 16-j slice
  short8 kf[8];
#pragma unroll
  for (int nt = 0; nt < 4; nt++)
#pragma unroll
    for (int kk = 0; kk < 2; kk++)
      kf[nt * 2 + kk] = *(const short8*)(Kb + (size_t)(nt * 16 + l16) * 64 + kk * 32 + quad * 8);

  for (int jt = 0; jt < 64; jt++) {
    const int j0 = jt * 64;
    // ---- S = Q K^T : lane holds S[i=quad*4+r][j=nt*16+l16]
    float4v sf[4];
#pragma unroll
    for (int nt = 0; nt < 4; nt++) sf[nt] = zz;
#pragma unroll
    for (int nt = 0; nt < 4; nt++)
#pragma unroll
      for (int kk = 0; kk < 2; kk++)
        sf[nt] = __builtin_amdgcn_mfma_f32_16x16x32_bf16(qf[kk], kf[nt * 2 + kk], sf[nt], 0, 0, 0);

    // ---- prefetch next K tile (wraps at end; harmless)
    {
      const int jn = ((jt + 1) & 63) * 64;
#pragma unroll
      for (int nt = 0; nt < 4; nt++)
#pragma unroll
        for (int kk = 0; kk < 2; kk++)
          kf[nt * 2 + kk] = *(const short8*)(Kb + (size_t)(jn + nt * 16 + l16) * 64 + kk * 32 + quad * 8);
    }

    // ---- tile-scalar online max (wave-uniform)
    float tm = sf[0][0];
#pragma unroll
    for (int nt = 0; nt < 4; nt++)
#pragma unroll
      for (int r = 0; r < 4; r++) tm = fmaxf(tm, sf[nt][r]);
#pragma unroll
    for (int s = 1; s < 64; s <<= 1) tm = fmaxf(tm, __shfl_xor(tm, s));
    const float mn = fmaxf(m, tm * SCL);
    float a = 1.0f;
    if (mn > m) {
      a = exp2f(m - mn);
#pragma unroll
      for (int nt = 0; nt < 16; nt++)
#pragma unroll
        for (int r = 0; r < 4; r++) of[nt][r] *= a;
    }
    m = mn;

    // ---- P = exp2(S*SCL - m); write bf16 to private LDS; row sums
    float rs[4] = {0.f, 0.f, 0.f, 0.f};
#pragma unroll
    for (int nt = 0; nt < 4; nt++)
#pragma unroll
      for (int r = 0; r < 4; r++) {
        float p = exp2f(__builtin_fmaf(sf[nt][r], SCL, -m));
        Pls[w][quad * 4 + r][nt * 16 + l16] = f2bf_fast(p);
        rs[r] += p;
      }
#pragma unroll
    for (int r = 0; r < 4; r++) {
      float v = rs[r];
      v += __shfl_xor(v, 1, 16);
      v += __shfl_xor(v, 2, 16);
      v += __shfl_xor(v, 4, 16);
      v += __shfl_xor(v, 8, 16);
      lsum[r] = lsum[r] * a + v;
    }

    // pin LDS write->read order (same wave; DS is in-order per wave)
    __builtin_amdgcn_sched_barrier(0);
    __builtin_amdgcn_s_waitcnt(0xC07F);   // lgkmcnt(0)
    __builtin_amdgcn_sched_barrier(0);

    // ---- O^T += V P : D[m=c][n=i]
#pragma unroll
    for (int kk = 0; kk < 2; kk++) {
      short8 pfr = *(const short8*)&Pls[w][l16][kk * 32 + quad * 8];
#pragma unroll
      for (int nt = 0; nt < 16; nt++) {
        short8 vf = *(const short8*)(Vb + (size_t)(nt * 16 + l16) * HW + j0 + kk * 32 + quad * 8);
        of[nt] = __builtin_amdgcn_mfma_f32_16x16x32_bf16(vf, pfr, of[nt], 0, 0, 0);
      }
    }
  }

  // ---- redistribute l: lane needs l[row = l16]; rows quad*4+r live in quad l16>>2
  float t0 = __shfl(lsum[0], (l16 >> 2) * 16);
  float t1 = __shfl(lsum[1], (l16 >> 2) * 16);
  float t2 = __shfl(lsum[2], (l16 >> 2) * 16);
  float t3 = __shfl(lsum[3], (l16 >> 2) * 16);
  float lv = (l16 & 1) ? ((l16 & 2) ? t3 : t1) : ((l16 & 2) ? t2 : t0);
  float inv = 1.0f / lv;

#pragma unroll
  for (int nt = 0; nt < 16; nt++)
#pragma unroll
    for (int r = 0; r < 4; r++)
      out[(size_t)(b * 256 + nt * 16 + quad * 4 + r) * HW + i0 + l16] = of[nt][r] * inv;
}

extern "C" void kernel_launch(void* const* d_in, const int* in_sizes, int n_in,
                              void* d_out, int out_size, void* d_ws, size_t ws_size,
                              hipStream_t stream) {
  const float* x  = (const float*)d_in[0];
  const float* qw = (const float*)d_in[1];
  const float* qb = (const float*)d_in[2];
  const float* kw = (const float*)d_in[3];
  const float* kb = (const float*)d_in[4];
  const float* vw = (const float*)d_in[5];
  const float* vb = (const float*)d_in[6];
  float* out = (float*)d_out;
  char* ws = (char*)d_ws;
  u16*   Xtp = (u16*)(ws);
  u16*   Wt  = (u16*)(ws + 8921088);
  float* bc  = (float*)(ws + 10690560);
  u16*   Qt  = (u16*)(ws + 10692096);
  u16*   Kt  = (u16*)(ws + 12789248);
  u16*   Vcf = (u16*)(ws + 14886400);

  hipMemsetAsync(Xtp, 0, 8921088, stream);  // zero the spatial halo
  k_xt  <<<dim3(128, 8, 4), 256, 0, stream>>>(x, Xtp);
  k_wprep<<<3456, 256, 0, stream>>>(qw, qb, kw, kb, vw, vb, Wt, bc);
  k_conv<<<dim3(32, 3, 4), 256, 0, stream>>>(Xtp, Wt, bc, Qt, Kt, Vcf);
  k_attn<<<dim3(64, 4), 256, 0, stream>>>(Qt, Kt, Vcf, out);
}